// Round 9
// baseline (326.257 us; speedup 1.0000x reference)
//
#include <hip/hip_runtime.h>
#include <hip/hip_bf16.h>

typedef unsigned short u16;
typedef short short8 __attribute__((ext_vector_type(8)));
typedef float floatx4 __attribute__((ext_vector_type(4)));

#define MFMA16(a, b, c) __builtin_amdgcn_mfma_f32_16x16x32_bf16((a), (b), (c), 0, 0, 0)

union U128u { uint4 q; u16 s[8]; };

__device__ __forceinline__ u16 f2bf(float f) {
  union { float f; unsigned u; } v; v.f = f;
  unsigned r = v.u + 0x7fffu + ((v.u >> 16) & 1u);
  return (u16)(r >> 16);
}

__device__ __forceinline__ float bf2f(u16 s) {
  union { unsigned u; float f; } v; v.u = ((unsigned)s) << 16;
  return v.f;
}

// pack two f32 -> bf16x2 (round-half-up) with one v_perm
__device__ __forceinline__ unsigned pk2(float hi, float lo) {
  union { float f; unsigned u; } a, b;
  a.f = hi; b.f = lo;
  return __builtin_amdgcn_perm(a.u + 0x8000u, b.u + 0x8000u, 0x07060302u);
}

__device__ __forceinline__ float fexp2(float x) {
#if __has_builtin(__builtin_amdgcn_exp2f)
  return __builtin_amdgcn_exp2f(x);
#else
  return exp2f(x);
#endif
}

// async global->LDS, 16B per lane. lds pointer must be wave-uniform. (GEMMs only.)
__device__ __forceinline__ void async16(const u16* g, u16* l) {
  __builtin_amdgcn_global_load_lds(
      (const __attribute__((address_space(1))) unsigned int*)g,
      (__attribute__((address_space(3))) unsigned int*)l, 16, 0, 0);
}

// ---------------- merged prep: cast x, cast Wo, repack Wqkv + biases ----------------

__global__ __launch_bounds__(256) void prep_all(
    const float* __restrict__ x, const float* __restrict__ Wo,
    const float* __restrict__ Wq, const float* __restrict__ bq,
    const float* __restrict__ Wk, const float* __restrict__ bk,
    const float* __restrict__ Wv, const float* __restrict__ bv,
    u16* __restrict__ Xb, u16* __restrict__ Wob,
    u16* __restrict__ Wt, float* __restrict__ ball) {
  int bid = blockIdx.x;
  int tid = threadIdx.x;
  if (bid < 5120) {
    // cast: blocks [0,4096) -> x (1048576 float4), [4096,5120) -> Wo (262144 float4)
    const float* src = bid < 4096 ? x : Wo;
    u16* dst = bid < 4096 ? Xb : Wob;
    int i = (bid < 4096 ? bid : bid - 4096) * 256 + tid;
    float4 v = ((const float4*)src)[i];
    union { unsigned long long ll; u16 s[4]; } o;
    o.s[0] = f2bf(v.x); o.s[1] = f2bf(v.y); o.s[2] = f2bf(v.z); o.s[3] = f2bf(v.w);
    ((unsigned long long*)dst)[i] = o.ll;
    return;
  }
  int id = (bid - 5120) * 256 + tid;  // 786432 total
  int kk4 = id & 15;
  int d = (id >> 4) & 1023;
  int h = (id >> 14) & 15;
  int wsel = id >> 18;
  const float* W = wsel == 0 ? Wq : (wsel == 1 ? Wk : Wv);
  float4 v = *(const float4*)(W + ((size_t)(h * 1024 + d)) * 64 + kk4 * 4);
  int nb = wsel * 1024 + h * 64 + kk4 * 4;
  Wt[(size_t)(nb + 0) * 1024 + d] = f2bf(v.x);
  Wt[(size_t)(nb + 1) * 1024 + d] = f2bf(v.y);
  Wt[(size_t)(nb + 2) * 1024 + d] = f2bf(v.z);
  Wt[(size_t)(nb + 3) * 1024 + d] = f2bf(v.w);
  if (id < 3072) {
    int ws2 = id >> 10, hk = id & 1023;
    const float* bsrc = ws2 == 0 ? bq : (ws2 == 1 ? bk : bv);
    ball[id] = bsrc[hk];
  }
}

// Vtc[bh][chunk v(128)][oct o(2)][d(64)][k(8)] <- QKV V-part; chunk = 16 seq positions
__global__ __launch_bounds__(256) void transpose_v(const u16* __restrict__ QKV,
                                                   u16* __restrict__ Vtc) {
  __shared__ u16 t[64][65];
  int tid = threadIdx.x;
  int bh = blockIdx.y, b = bh >> 4, h = bh & 15;
  int s0 = blockIdx.x * 64;          // 64 seq rows per block
  int v0 = blockIdx.x * 4;           // 4 chunks per block
  {
    int r = tid >> 2, c0 = (tid & 3) * 16;
    const u16* src = QKV + (size_t)(b * 2048 + s0 + r) * 3072 + 2048 + h * 64 + c0;
    U128u a, c;
    a.q = *(const uint4*)src;
    c.q = *(const uint4*)(src + 8);
#pragma unroll
    for (int j = 0; j < 8; ++j) { t[r][c0 + j] = a.s[j]; t[r][c0 + 8 + j] = c.s[j]; }
  }
  __syncthreads();
  {
    int g = tid;
#pragma unroll
    for (int gg = 0; gg < 2; ++gg, g += 256) {
      int d = g & 63, o = (g >> 6) & 1, vloc = g >> 7;
      int sl = vloc * 16 + o * 8;
      U128u out;
#pragma unroll
      for (int k = 0; k < 8; ++k) out.s[k] = t[sl + k][d];
      u16* dst = Vtc + (((size_t)(bh * 128 + v0 + vloc) * 2 + o) * 64 + d) * 8;
      *(uint4*)dst = out.q;
    }
  }
}

// ---------------- GEMM: C[M,N] = A[M,K] * B^T (B stored [N,K]) + bias, opt scale ----------------
// 1-D grid, XCD-swizzled: xcd owns bm cluster of 4 (keeps A-tiles in per-XCD L2).

__device__ __forceinline__ void store_out(u16* p, float v) { *p = f2bf(v); }
__device__ __forceinline__ void store_out(float* p, float v) { *p = v; }

template <int BN, typename OutT>
__global__ __launch_bounds__(256) void gemm_bt(
    const u16* __restrict__ A, const u16* __restrict__ B,
    const float* __restrict__ bias, OutT* __restrict__ C,
    int M, int N, int K, int scaleNend, float scaleVal) {
  constexpr int TN = BN / 32;  // n-tiles per wave
  __shared__ __attribute__((aligned(16))) u16 As[128 * 32];
  __shared__ __attribute__((aligned(16))) u16 Bs[BN * 32];
  const int tid = threadIdx.x;
  const int w = tid >> 6, lane = tid & 63;
  const int l15 = lane & 15, l4 = lane >> 4;
  const int lin = blockIdx.x;
  const int xcd = lin & 7, sblk = lin >> 3;
  const int bm = xcd * 4 + (sblk & 3);   // M=4096 -> 32 bm tiles, 4 per XCD
  const int bn = sblk >> 2;
  const int wm = (w & 1) * 64, wn = (w >> 1) * (BN / 2);

  floatx4 acc[4][TN];
#pragma unroll
  for (int i = 0; i < 4; ++i)
#pragma unroll
    for (int j = 0; j < TN; ++j) acc[i][j] = (floatx4){0.f, 0.f, 0.f, 0.f};

  for (int k0 = 0; k0 < K; k0 += 32) {
    __syncthreads();
#pragma unroll
    for (int j = 0; j < 2; ++j) {
      int i = j * 256 + tid;
      int row = i >> 2, ko = (i & 3) * 8;
      async16(A + (size_t)(bm * 128 + row) * K + k0 + ko, As + (j * 256 + w * 64) * 8);
    }
#pragma unroll
    for (int j = 0; j < BN / 64; ++j) {
      int i = j * 256 + tid;
      int row = i >> 2, ko = (i & 3) * 8;
      async16(B + (size_t)(bn * BN + row) * K + k0 + ko, Bs + (j * 256 + w * 64) * 8);
    }
    __syncthreads();
    short8 af[4], bf[TN];
#pragma unroll
    for (int t = 0; t < 4; ++t)
      af[t] = *(const short8*)(As + (wm + t * 16 + l15) * 32 + l4 * 8);
#pragma unroll
    for (int t = 0; t < TN; ++t)
      bf[t] = *(const short8*)(Bs + (wn + t * 16 + l15) * 32 + l4 * 8);
#pragma unroll
    for (int tm = 0; tm < 4; ++tm)
#pragma unroll
      for (int tn = 0; tn < TN; ++tn) acc[tm][tn] = MFMA16(af[tm], bf[tn], acc[tm][tn]);
  }

#pragma unroll
  for (int tn = 0; tn < TN; ++tn) {
    int col = bn * BN + wn + tn * 16 + l15;
    float bv = bias[col];
    float sc = (col < scaleNend) ? scaleVal : 1.0f;
#pragma unroll
    for (int tm = 0; tm < 4; ++tm) {
      int row0 = bm * 128 + wm + tm * 16 + l4 * 4;
#pragma unroll
      for (int r = 0; r < 4; ++r) {
        float v = (acc[tm][tn][r] + bv) * sc;
        store_out(C + (size_t)(row0 + r) * N + col, v);
      }
    }
  }
}

// ---------------- attention (round-6 structure + register-level K double-buffering) ----------------
// Block: 64 q-rows of one (b,h); wave w owns keys [w*512,(w+1)*512), ALL 64 q-rows (tq=4).
// K/V fragments register-direct from L2 (no global_load_lds, no barriers in key loop).
// The superstep loop is unrolled x2 with explicit kfA/kfB buffers (no register copies):
// next superstep's K loads are in flight across the whole current compute, V loads are
// issued a whole compute-phase before consumption -> partial-vmcnt waits only, never a
// load-latency drain (round-6/8's stall was kf/vf register recycling serializing on L2).
// PV uses K=32 bf16 MFMA via the per-wave LDS P round-trip (measured r8: the K=16 f16
// "in-register P" path costs the SAME ~19cyc/SIMD per MFMA -> 2x matrix-pipe waste).
// XCD swizzle: 4 bh per XCD -> K/V (2MB) L2-resident (r3: FETCH 12.5MB).
// Q pre-scaled log2(e)/8 -> raw exp2; unnormalized accumulate (flat softmax, max-free
// safe); per-wave partials combined once in LDS at the end (single barrier).

__global__ __launch_bounds__(256, 3) void attn_kernel(const u16* __restrict__ QKV,
                                                      const u16* __restrict__ Vtc,
                                                      u16* __restrict__ Ob) {
  // per-wave region: 4736 u16 = P[64 q][stride 40] (2560) overlapped by
  // Osum bf16 [64][stride 72] (4608) + l f32[64] at offset 4608.
  __shared__ __attribute__((aligned(16))) u16 lds[4 * 4736];  // 37888 B
  const int tid = threadIdx.x;
  const int w = tid >> 6, lane = tid & 63;
  const int l15 = lane & 15, l4 = lane >> 4;
  const int lin = blockIdx.x;                 // 1024 blocks
  const int xcd = lin & 7, sblk = lin >> 3;   // sblk in [0,128)
  const int bh = xcd * 4 + (sblk & 3);        // 4 bh per XCD
  const int q0 = (sblk >> 2) * 64;            // 32 q-tiles of 64
  const int b = bh >> 4, h = bh & 15;

  u16* const Pw = lds + w * 4736;

  // Q fragments (B-operand of S^T): rows q0 + tq*16 + l15, k(d) = s*32 + l4*8
  short8 qf[4][2];
  {
    const u16* Qb = QKV + (size_t)(b * 2048 + q0) * 3072 + h * 64;
#pragma unroll
    for (int tq = 0; tq < 4; ++tq)
#pragma unroll
      for (int s = 0; s < 2; ++s)
        qf[tq][s] = *(const short8*)(Qb + (size_t)(tq * 16 + l15) * 3072 + s * 32 + l4 * 8);
  }

  floatx4 Oacc[4][4];
#pragma unroll
  for (int i = 0; i < 4; ++i)
#pragma unroll
    for (int j = 0; j < 4; ++j) Oacc[i][j] = (floatx4){0.f, 0.f, 0.f, 0.f};
  float lpart[4] = {0.f, 0.f, 0.f, 0.f};

  const u16* const Kb = QKV + (size_t)(b * 2048) * 3072 + 1024 + h * 64;  // + key*3072
  const u16* const Vw = Vtc + (size_t)bh * 131072 + (size_t)w * 32768;    // wave's 512 keys
  const int kw0 = w * 512;

  short8 kfA[2][2], kfB[2][2], vf[4];

  // K fragments (A-operand of S^T): key = kw0 + c*32 + t*16 + l15, d = s*32 + l4*8
  auto loadK = [&](short8 (&kf)[2][2], int c) {
    const u16* src = Kb + (size_t)(kw0 + c * 32) * 3072;
#pragma unroll
    for (int t = 0; t < 2; ++t)
#pragma unroll
      for (int s = 0; s < 2; ++s)
        kf[t][s] = *(const short8*)(src + (size_t)(t * 16 + l15) * 3072 + s * 32 + l4 * 8);
  };
  // V fragments (B-operand of PV): d = td*16+l15, keys l4*8..+8 of the 32-key superstep
  auto loadV = [&](int c) {
#pragma unroll
    for (int td = 0; td < 4; ++td)
      vf[td] = *(const short8*)(Vw + (size_t)c * 2048 + l4 * 512 + (td * 16 + l15) * 8);
  };
  // one 32-key superstep: S^T -> exp -> P (LDS) -> PV, on given K buffer + current vf
  auto compute = [&](short8 (&kf)[2][2]) {
#pragma unroll
    for (int t = 0; t < 2; ++t)
#pragma unroll
      for (int tq = 0; tq < 4; ++tq) {
        floatx4 s = (floatx4){0.f, 0.f, 0.f, 0.f};
        s = MFMA16(kf[t][0], qf[tq][0], s);
        s = MFMA16(kf[t][1], qf[tq][1], s);
        float p0 = fexp2(s[0]), p1 = fexp2(s[1]), p2 = fexp2(s[2]), p3 = fexp2(s[3]);
        lpart[tq] += (p0 + p1) + (p2 + p3);
        unsigned lo = pk2(p1, p0), hi = pk2(p3, p2);
        *(unsigned long long*)(Pw + (size_t)(tq * 16 + l15) * 40 + t * 16 + l4 * 4) =
            ((unsigned long long)hi << 32) | lo;
      }
    short8 pf[4];
#pragma unroll
    for (int tq = 0; tq < 4; ++tq)
      pf[tq] = *(const short8*)(Pw + (size_t)(tq * 16 + l15) * 40 + l4 * 8);
#pragma unroll
    for (int td = 0; td < 4; ++td)
#pragma unroll
      for (int tq = 0; tq < 4; ++tq) Oacc[tq][td] = MFMA16(pf[tq], vf[td], Oacc[tq][td]);
  };

  loadK(kfA, 0);
  for (int c = 0; c < 16; c += 2) {
    loadV(c);
    loadK(kfB, c + 1);
    compute(kfA);
    loadV(c + 1);
    loadK(kfA, c + 2 < 16 ? c + 2 : 15);  // harmless re-load on last iter (branchless)
    compute(kfB);
  }

  // per-wave l reduction across l4 key-groups (full 512-key sums per q)
  float lr[4];
#pragma unroll
  for (int tq = 0; tq < 4; ++tq) {
    float l = lpart[tq];
    l += __shfl_xor(l, 16);
    l += __shfl_xor(l, 32);
    lr[tq] = l;
  }

  // write per-wave partials (own region; own P reads already retired in-order)
#pragma unroll
  for (int tq = 0; tq < 4; ++tq)
#pragma unroll
    for (int td = 0; td < 4; ++td)
#pragma unroll
      for (int r = 0; r < 4; ++r)
        Pw[(size_t)(tq * 16 + l4 * 4 + r) * 72 + td * 16 + l15] = f2bf(Oacc[tq][td][r]);
  if (l4 == 0) {
    float* Lw = (float*)(Pw + 4608);
#pragma unroll
    for (int tq = 0; tq < 4; ++tq) Lw[tq * 16 + l15] = lr[tq];
  }
  __syncthreads();

  // combine: thread -> (row = tid>>2 of 64, 16 cols); sum 4 wave partials
  {
    int row = tid >> 2, c0 = (tid & 3) * 16;
    float acc[16];
#pragma unroll
    for (int j = 0; j < 16; ++j) acc[j] = 0.f;
    float lsum = 0.f;
#pragma unroll
    for (int wv = 0; wv < 4; ++wv) {
      const u16* R = lds + wv * 4736;
      lsum += ((const float*)(R + 4608))[row];
      U128u x1, x2;
      x1.q = *(const uint4*)(R + (size_t)row * 72 + c0);
      x2.q = *(const uint4*)(R + (size_t)row * 72 + c0 + 8);
#pragma unroll
      for (int j = 0; j < 8; ++j) { acc[j] += bf2f(x1.s[j]); acc[8 + j] += bf2f(x2.s[j]); }
    }
    float inv = 1.0f / lsum;
    U128u o1, o2;
#pragma unroll
    for (int j = 0; j < 8; ++j) { o1.s[j] = f2bf(acc[j] * inv); o2.s[j] = f2bf(acc[8 + j] * inv); }
    u16* Op = Ob + (size_t)(b * 2048 + q0 + row) * 1024 + h * 64 + c0;
    *(uint4*)Op = o1.q;
    *(uint4*)(Op + 8) = o2.q;
  }
}

// ---------------- launch ----------------

extern "C" void kernel_launch(void* const* d_in, const int* in_sizes, int n_in,
                              void* d_out, int out_size, void* d_ws, size_t ws_size,
                              hipStream_t stream) {
  const float* x  = (const float*)d_in[0];
  const float* Wq = (const float*)d_in[1];
  const float* bq = (const float*)d_in[2];
  const float* Wk = (const float*)d_in[3];
  const float* bk = (const float*)d_in[4];
  const float* Wv = (const float*)d_in[5];
  const float* bv = (const float*)d_in[6];
  const float* Wo = (const float*)d_in[7];
  const float* bo = (const float*)d_in[8];

  char* p = (char*)d_ws;
  u16* Xb   = (u16*)p; p += (size_t)4096 * 1024 * 2;   // x bf16
  u16* Wt   = (u16*)p; p += (size_t)3072 * 1024 * 2;   // W_all^T bf16 [n][d]
  u16* QKV  = (u16*)p; p += (size_t)4096 * 3072 * 2;   // [token][3072] bf16 (Q pre-scaled log2e/8)
  u16* Vtc  = (u16*)p; p += (size_t)32 * 128 * 2 * 64 * 8 * 2;  // V chunked: [bh][v][o][d][k8]
  u16* Ob   = (u16*)p; p += (size_t)4096 * 1024 * 2;   // attention out bf16 (normalized)
  u16* Wob  = (u16*)p; p += (size_t)1024 * 1024 * 2;   // Wo bf16 [e][d]
  float* ball = (float*)p; p += 3072 * sizeof(float);

  const float qscale = 0.125f * 1.4426950408889634f;  // (1/sqrt(64)) * log2(e)

  prep_all<<<8192, 256, 0, stream>>>(x, Wo, Wq, bq, Wk, bk, Wv, bv, Xb, Wob, Wt, ball);
  gemm_bt<128, u16><<<768, 256, 0, stream>>>(Xb, Wt, ball, QKV,
                                             4096, 3072, 1024, 1024, qscale);
  transpose_v<<<dim3(32, 32), 256, 0, stream>>>(QKV, Vtc);
  attn_kernel<<<1024, 256, 0, stream>>>(QKV, Vtc, Ob);
  gemm_bt<64, float><<<512, 256, 0, stream>>>(Ob, Wob, bo, (float*)d_out,
                                              4096, 1024, 1024, 0, 1.0f);
}

// Round 10
// 215.871 us; speedup vs baseline: 1.5113x; 1.5113x over previous
//
#include <hip/hip_runtime.h>
#include <hip/hip_bf16.h>

typedef unsigned short u16;
typedef short short8 __attribute__((ext_vector_type(8)));
typedef float floatx4 __attribute__((ext_vector_type(4)));

#define MFMA16(a, b, c) __builtin_amdgcn_mfma_f32_16x16x32_bf16((a), (b), (c), 0, 0, 0)

union U128u { uint4 q; u16 s[8]; };

__device__ __forceinline__ u16 f2bf(float f) {
  union { float f; unsigned u; } v; v.f = f;
  unsigned r = v.u + 0x7fffu + ((v.u >> 16) & 1u);
  return (u16)(r >> 16);
}

__device__ __forceinline__ float bf2f(u16 s) {
  union { unsigned u; float f; } v; v.u = ((unsigned)s) << 16;
  return v.f;
}

// pack two f32 -> bf16x2 (round-half-up) with one v_perm
__device__ __forceinline__ unsigned pk2(float hi, float lo) {
  union { float f; unsigned u; } a, b;
  a.f = hi; b.f = lo;
  return __builtin_amdgcn_perm(a.u + 0x8000u, b.u + 0x8000u, 0x07060302u);
}

__device__ __forceinline__ float fexp2(float x) {
#if __has_builtin(__builtin_amdgcn_exp2f)
  return __builtin_amdgcn_exp2f(x);
#else
  return exp2f(x);
#endif
}

// async global->LDS, 16B per lane. lds pointer must be wave-uniform. (GEMMs only.)
__device__ __forceinline__ void async16(const u16* g, u16* l) {
  __builtin_amdgcn_global_load_lds(
      (const __attribute__((address_space(1))) unsigned int*)g,
      (__attribute__((address_space(3))) unsigned int*)l, 16, 0, 0);
}

// ---------------- merged prep: cast x, cast Wo, repack Wqkv + biases ----------------

__global__ __launch_bounds__(256) void prep_all(
    const float* __restrict__ x, const float* __restrict__ Wo,
    const float* __restrict__ Wq, const float* __restrict__ bq,
    const float* __restrict__ Wk, const float* __restrict__ bk,
    const float* __restrict__ Wv, const float* __restrict__ bv,
    u16* __restrict__ Xb, u16* __restrict__ Wob,
    u16* __restrict__ Wt, float* __restrict__ ball) {
  int bid = blockIdx.x;
  int tid = threadIdx.x;
  if (bid < 5120) {
    // cast: blocks [0,4096) -> x (1048576 float4), [4096,5120) -> Wo (262144 float4)
    const float* src = bid < 4096 ? x : Wo;
    u16* dst = bid < 4096 ? Xb : Wob;
    int i = (bid < 4096 ? bid : bid - 4096) * 256 + tid;
    float4 v = ((const float4*)src)[i];
    union { unsigned long long ll; u16 s[4]; } o;
    o.s[0] = f2bf(v.x); o.s[1] = f2bf(v.y); o.s[2] = f2bf(v.z); o.s[3] = f2bf(v.w);
    ((unsigned long long*)dst)[i] = o.ll;
    return;
  }
  int id = (bid - 5120) * 256 + tid;  // 786432 total
  int kk4 = id & 15;
  int d = (id >> 4) & 1023;
  int h = (id >> 14) & 15;
  int wsel = id >> 18;
  const float* W = wsel == 0 ? Wq : (wsel == 1 ? Wk : Wv);
  float4 v = *(const float4*)(W + ((size_t)(h * 1024 + d)) * 64 + kk4 * 4);
  int nb = wsel * 1024 + h * 64 + kk4 * 4;
  Wt[(size_t)(nb + 0) * 1024 + d] = f2bf(v.x);
  Wt[(size_t)(nb + 1) * 1024 + d] = f2bf(v.y);
  Wt[(size_t)(nb + 2) * 1024 + d] = f2bf(v.z);
  Wt[(size_t)(nb + 3) * 1024 + d] = f2bf(v.w);
  if (id < 3072) {
    int ws2 = id >> 10, hk = id & 1023;
    const float* bsrc = ws2 == 0 ? bq : (ws2 == 1 ? bk : bv);
    ball[id] = bsrc[hk];
  }
}

// ---------------- GEMM: C[M,N] = A[M,K] * B^T (B stored [N,K]) + bias, opt scale --------------
// 1-D grid, XCD-swizzled: xcd owns bm cluster of 4 (keeps A-tiles in per-XCD L2).
// SPLITV (QKV mode): cols >= 2048 (the V projection) are written DIRECTLY in the Vtc
// attention layout [bh][chunk s/16][oct (s%16)/8][d][s%8] instead of to C -- this fuses
// the old transpose_v kernel (and its 24 MB of traffic) into the epilogue. Bit-identical:
// same f2bf of the same accumulator value. col<2048 test is wave-uniform (16-col tiles).

__device__ __forceinline__ void store_out(u16* p, float v) { *p = f2bf(v); }
__device__ __forceinline__ void store_out(float* p, float v) { *p = v; }

template <int BN, bool SPLITV, typename OutT>
__global__ __launch_bounds__(256) void gemm_bt(
    const u16* __restrict__ A, const u16* __restrict__ B,
    const float* __restrict__ bias, OutT* __restrict__ C,
    u16* __restrict__ Vtc,
    int M, int N, int K, int scaleNend, float scaleVal) {
  constexpr int TN = BN / 32;  // n-tiles per wave
  __shared__ __attribute__((aligned(16))) u16 As[128 * 32];
  __shared__ __attribute__((aligned(16))) u16 Bs[BN * 32];
  const int tid = threadIdx.x;
  const int w = tid >> 6, lane = tid & 63;
  const int l15 = lane & 15, l4 = lane >> 4;
  const int lin = blockIdx.x;
  const int xcd = lin & 7, sblk = lin >> 3;
  const int bm = xcd * 4 + (sblk & 3);   // M=4096 -> 32 bm tiles, 4 per XCD
  const int bn = sblk >> 2;
  const int wm = (w & 1) * 64, wn = (w >> 1) * (BN / 2);

  floatx4 acc[4][TN];
#pragma unroll
  for (int i = 0; i < 4; ++i)
#pragma unroll
    for (int j = 0; j < TN; ++j) acc[i][j] = (floatx4){0.f, 0.f, 0.f, 0.f};

  for (int k0 = 0; k0 < K; k0 += 32) {
    __syncthreads();
#pragma unroll
    for (int j = 0; j < 2; ++j) {
      int i = j * 256 + tid;
      int row = i >> 2, ko = (i & 3) * 8;
      async16(A + (size_t)(bm * 128 + row) * K + k0 + ko, As + (j * 256 + w * 64) * 8);
    }
#pragma unroll
    for (int j = 0; j < BN / 64; ++j) {
      int i = j * 256 + tid;
      int row = i >> 2, ko = (i & 3) * 8;
      async16(B + (size_t)(bn * BN + row) * K + k0 + ko, Bs + (j * 256 + w * 64) * 8);
    }
    __syncthreads();
    short8 af[4], bf[TN];
#pragma unroll
    for (int t = 0; t < 4; ++t)
      af[t] = *(const short8*)(As + (wm + t * 16 + l15) * 32 + l4 * 8);
#pragma unroll
    for (int t = 0; t < TN; ++t)
      bf[t] = *(const short8*)(Bs + (wn + t * 16 + l15) * 32 + l4 * 8);
#pragma unroll
    for (int tm = 0; tm < 4; ++tm)
#pragma unroll
      for (int tn = 0; tn < TN; ++tn) acc[tm][tn] = MFMA16(af[tm], bf[tn], acc[tm][tn]);
  }

#pragma unroll
  for (int tn = 0; tn < TN; ++tn) {
    int col = bn * BN + wn + tn * 16 + l15;
    float bv = bias[col];
    float sc = (col < scaleNend) ? scaleVal : 1.0f;
    if (!SPLITV || col < 2048) {
#pragma unroll
      for (int tm = 0; tm < 4; ++tm) {
        int row0 = bm * 128 + wm + tm * 16 + l4 * 4;
#pragma unroll
        for (int r = 0; r < 4; ++r) {
          float v = (acc[tm][tn][r] + bv) * sc;
          store_out(C + (size_t)(row0 + r) * N + col, v);
        }
      }
    } else {
      int hv = (col - 2048) >> 6, d = (col - 2048) & 63;
#pragma unroll
      for (int tm = 0; tm < 4; ++tm) {
        int row0 = bm * 128 + wm + tm * 16 + l4 * 4;
#pragma unroll
        for (int r = 0; r < 4; ++r) {
          float v = acc[tm][tn][r] + bv;
          int row = row0 + r;
          int bb = row >> 11, s = row & 2047;
          size_t idx = ((((size_t)(bb * 16 + hv) * 128 + (s >> 4)) * 2 + ((s >> 3) & 1)) * 64 + d) * 8 +
                       (s & 7);
          Vtc[idx] = f2bf(v);
        }
      }
    }
  }
}

// ---------------- attention (round-6 proven: barrier-free, register-direct K/V) ----------------
// Block: 64 q-rows of one (b,h); wave w owns keys [w*512,(w+1)*512), ALL 64 q-rows (tq=4).
// K and V fragments are loaded straight from L2 to VGPRs (plain dwordx4 per lane; MFMA
// fragment = 16B contiguous per lane) -- NO global_load_lds, NO staging LDS, NO barriers
// in the key loop, so there is no vmcnt(0)+s_barrier drain.
// LDS is only the per-wave P round-trip + one-time cross-wave O/l combine (1 barrier).
// XCD swizzle: 4 bh per XCD -> K/V (2MB) L2-resident (r3: FETCH 12.5MB).
// Q pre-scaled by log2(e)/8 -> raw exp2; unnormalized accumulate (flat softmax, max-free
// safe); divide once at the end. [r9 lesson: NO manual register double-buffering --
// lambda-rotated K buffers made the compiler spill 540 MB of scratch traffic.]

__global__ __launch_bounds__(256, 3) void attn_kernel(const u16* __restrict__ QKV,
                                                      const u16* __restrict__ Vtc,
                                                      u16* __restrict__ Ob) {
  // per-wave region: 4736 u16 = P[64 q][stride 40] (2560) overlapped by
  // Osum bf16 [64][stride 72] (4608) + l f32[64] at offset 4608.
  __shared__ __attribute__((aligned(16))) u16 lds[4 * 4736];  // 37888 B
  const int tid = threadIdx.x;
  const int w = tid >> 6, lane = tid & 63;
  const int l15 = lane & 15, l4 = lane >> 4;
  const int lin = blockIdx.x;                 // 1024 blocks
  const int xcd = lin & 7, sblk = lin >> 3;   // sblk in [0,128)
  const int bh = xcd * 4 + (sblk & 3);        // 4 bh per XCD
  const int q0 = (sblk >> 2) * 64;            // 32 q-tiles of 64
  const int b = bh >> 4, h = bh & 15;

  u16* const Pw = lds + w * 4736;

  // Q fragments (B-operand of S^T): rows q0 + tq*16 + l15, k(d) = s*32 + l4*8
  short8 qf[4][2];
  {
    const u16* Qb = QKV + (size_t)(b * 2048 + q0) * 3072 + h * 64;
#pragma unroll
    for (int tq = 0; tq < 4; ++tq)
#pragma unroll
      for (int s = 0; s < 2; ++s)
        qf[tq][s] = *(const short8*)(Qb + (size_t)(tq * 16 + l15) * 3072 + s * 32 + l4 * 8);
  }

  floatx4 Oacc[4][4];
#pragma unroll
  for (int i = 0; i < 4; ++i)
#pragma unroll
    for (int j = 0; j < 4; ++j) Oacc[i][j] = (floatx4){0.f, 0.f, 0.f, 0.f};
  float lpart[4] = {0.f, 0.f, 0.f, 0.f};

  const u16* const Kb = QKV + (size_t)(b * 2048) * 3072 + 1024 + h * 64;  // + key*3072
  const u16* const Vw = Vtc + (size_t)bh * 131072 + (size_t)w * 32768;    // wave's 512 keys
  const int kw0 = w * 512;

  for (int c = 0; c < 16; ++c) {  // 32-key supersteps
    const int key0 = kw0 + c * 32;
    // K fragments (A-operand): A[m=key][k=d]; lane: key = key0 + t*16 + l15, d = s*32+l4*8
    short8 kf[2][2];
#pragma unroll
    for (int t = 0; t < 2; ++t)
#pragma unroll
      for (int s = 0; s < 2; ++s)
        kf[t][s] = *(const short8*)(Kb + (size_t)(key0 + t * 16 + l15) * 3072 + s * 32 + l4 * 8);
    // V fragments (B-operand): B[n=d][k=key]; lane: d = td*16+l15, keys l4*8..+8
    short8 vf[4];
#pragma unroll
    for (int td = 0; td < 4; ++td)
      vf[td] = *(const short8*)(Vw + (size_t)c * 2048 + l4 * 512 + (td * 16 + l15) * 8);

    // S^T: C[key16][q16]; row=key=l4*4+r, col=q=l15
#pragma unroll
    for (int t = 0; t < 2; ++t)
#pragma unroll
      for (int tq = 0; tq < 4; ++tq) {
        floatx4 s = (floatx4){0.f, 0.f, 0.f, 0.f};
        s = MFMA16(kf[t][0], qf[tq][0], s);
        s = MFMA16(kf[t][1], qf[tq][1], s);
        float p0 = fexp2(s[0]), p1 = fexp2(s[1]), p2 = fexp2(s[2]), p3 = fexp2(s[3]);
        lpart[tq] += (p0 + p1) + (p2 + p3);
        unsigned lo = pk2(p1, p0), hi = pk2(p3, p2);
        *(unsigned long long*)(Pw + (size_t)(tq * 16 + l15) * 40 + t * 16 + l4 * 4) =
            ((unsigned long long)hi << 32) | lo;
      }

    // PV: O[q][d] += P[q][k32] * V[k32][d]
    short8 pf[4];
#pragma unroll
    for (int tq = 0; tq < 4; ++tq)
      pf[tq] = *(const short8*)(Pw + (size_t)(tq * 16 + l15) * 40 + l4 * 8);
#pragma unroll
    for (int td = 0; td < 4; ++td)
#pragma unroll
      for (int tq = 0; tq < 4; ++tq) Oacc[tq][td] = MFMA16(pf[tq], vf[td], Oacc[tq][td]);
  }

  // per-wave l reduction across l4 key-groups (full 512-key sums per q)
  float lr[4];
#pragma unroll
  for (int tq = 0; tq < 4; ++tq) {
    float l = lpart[tq];
    l += __shfl_xor(l, 16);
    l += __shfl_xor(l, 32);
    lr[tq] = l;
  }

  // write per-wave partials (own region; own P reads already retired in-order)
#pragma unroll
  for (int tq = 0; tq < 4; ++tq)
#pragma unroll
    for (int td = 0; td < 4; ++td)
#pragma unroll
      for (int r = 0; r < 4; ++r)
        Pw[(size_t)(tq * 16 + l4 * 4 + r) * 72 + td * 16 + l15] = f2bf(Oacc[tq][td][r]);
  if (l4 == 0) {
    float* Lw = (float*)(Pw + 4608);
#pragma unroll
    for (int tq = 0; tq < 4; ++tq) Lw[tq * 16 + l15] = lr[tq];
  }
  __syncthreads();

  // combine: thread -> (row = tid>>2 of 64, 16 cols); sum 4 wave partials
  {
    int row = tid >> 2, c0 = (tid & 3) * 16;
    float acc[16];
#pragma unroll
    for (int j = 0; j < 16; ++j) acc[j] = 0.f;
    float lsum = 0.f;
#pragma unroll
    for (int wv = 0; wv < 4; ++wv) {
      const u16* R = lds + wv * 4736;
      lsum += ((const float*)(R + 4608))[row];
      U128u x1, x2;
      x1.q = *(const uint4*)(R + (size_t)row * 72 + c0);
      x2.q = *(const uint4*)(R + (size_t)row * 72 + c0 + 8);
#pragma unroll
      for (int j = 0; j < 8; ++j) { acc[j] += bf2f(x1.s[j]); acc[8 + j] += bf2f(x2.s[j]); }
    }
    float inv = 1.0f / lsum;
    U128u o1, o2;
#pragma unroll
    for (int j = 0; j < 8; ++j) { o1.s[j] = f2bf(acc[j] * inv); o2.s[j] = f2bf(acc[8 + j] * inv); }
    u16* Op = Ob + (size_t)(b * 2048 + q0 + row) * 1024 + h * 64 + c0;
    *(uint4*)Op = o1.q;
    *(uint4*)(Op + 8) = o2.q;
  }
}

// ---------------- launch ----------------

extern "C" void kernel_launch(void* const* d_in, const int* in_sizes, int n_in,
                              void* d_out, int out_size, void* d_ws, size_t ws_size,
                              hipStream_t stream) {
  const float* x  = (const float*)d_in[0];
  const float* Wq = (const float*)d_in[1];
  const float* bq = (const float*)d_in[2];
  const float* Wk = (const float*)d_in[3];
  const float* bk = (const float*)d_in[4];
  const float* Wv = (const float*)d_in[5];
  const float* bv = (const float*)d_in[6];
  const float* Wo = (const float*)d_in[7];
  const float* bo = (const float*)d_in[8];

  char* p = (char*)d_ws;
  u16* Xb   = (u16*)p; p += (size_t)4096 * 1024 * 2;   // x bf16
  u16* Wt   = (u16*)p; p += (size_t)3072 * 1024 * 2;   // W_all^T bf16 [n][d]
  u16* QKV  = (u16*)p; p += (size_t)4096 * 3072 * 2;   // [token][3072] bf16; Q pre-scaled, V third unused
  u16* Vtc  = (u16*)p; p += (size_t)32 * 128 * 2 * 64 * 8 * 2;  // V chunked: [bh][v][o][d][k8]
  u16* Ob   = (u16*)p; p += (size_t)4096 * 1024 * 2;   // attention out bf16 (normalized)
  u16* Wob  = (u16*)p; p += (size_t)1024 * 1024 * 2;   // Wo bf16 [e][d]
  float* ball = (float*)p; p += 3072 * sizeof(float);

  const float qscale = 0.125f * 1.4426950408889634f;  // (1/sqrt(64)) * log2(e)

  prep_all<<<8192, 256, 0, stream>>>(x, Wo, Wq, bq, Wk, bk, Wv, bv, Xb, Wob, Wt, ball);
  gemm_bt<128, true, u16><<<768, 256, 0, stream>>>(Xb, Wt, ball, QKV, Vtc,
                                                   4096, 3072, 1024, 1024, qscale);
  attn_kernel<<<1024, 256, 0, stream>>>(QKV, Vtc, Ob);
  gemm_bt<64, false, float><<<512, 256, 0, stream>>>(Ob, Wob, bo, (float*)d_out, nullptr,
                                                     4096, 1024, 1024, 0, 1.0f);
}

// Round 11
// 213.661 us; speedup vs baseline: 1.5270x; 1.0103x over previous
//
#include <hip/hip_runtime.h>
#include <hip/hip_bf16.h>

typedef unsigned short u16;
typedef short short8 __attribute__((ext_vector_type(8)));
typedef float floatx4 __attribute__((ext_vector_type(4)));

#define MFMA16(a, b, c) __builtin_amdgcn_mfma_f32_16x16x32_bf16((a), (b), (c), 0, 0, 0)

union U128u { uint4 q; u16 s[8]; };

__device__ __forceinline__ u16 f2bf(float f) {
  union { float f; unsigned u; } v; v.f = f;
  unsigned r = v.u + 0x7fffu + ((v.u >> 16) & 1u);
  return (u16)(r >> 16);
}

__device__ __forceinline__ float bf2f(u16 s) {
  union { unsigned u; float f; } v; v.u = ((unsigned)s) << 16;
  return v.f;
}

// pack two f32 -> bf16x2 (round-half-up) with one v_perm (attn P only)
__device__ __forceinline__ unsigned pk2(float hi, float lo) {
  union { float f; unsigned u; } a, b;
  a.f = hi; b.f = lo;
  return __builtin_amdgcn_perm(a.u + 0x8000u, b.u + 0x8000u, 0x07060302u);
}

__device__ __forceinline__ float fexp2(float x) {
#if __has_builtin(__builtin_amdgcn_exp2f)
  return __builtin_amdgcn_exp2f(x);
#else
  return exp2f(x);
#endif
}

// async global->LDS, 16B per lane. lds pointer must be wave-uniform. (GEMMs only.)
__device__ __forceinline__ void async16(const u16* g, u16* l) {
  __builtin_amdgcn_global_load_lds(
      (const __attribute__((address_space(1))) unsigned int*)g,
      (__attribute__((address_space(3))) unsigned int*)l, 16, 0, 0);
}

// ---------------- merged prep: cast x, cast Wo, repack Wqkv + biases ----------------

__global__ __launch_bounds__(256) void prep_all(
    const float* __restrict__ x, const float* __restrict__ Wo,
    const float* __restrict__ Wq, const float* __restrict__ bq,
    const float* __restrict__ Wk, const float* __restrict__ bk,
    const float* __restrict__ Wv, const float* __restrict__ bv,
    u16* __restrict__ Xb, u16* __restrict__ Wob,
    u16* __restrict__ Wt, float* __restrict__ ball) {
  int bid = blockIdx.x;
  int tid = threadIdx.x;
  if (bid < 5120) {
    // cast: blocks [0,4096) -> x (1048576 float4), [4096,5120) -> Wo (262144 float4)
    const float* src = bid < 4096 ? x : Wo;
    u16* dst = bid < 4096 ? Xb : Wob;
    int i = (bid < 4096 ? bid : bid - 4096) * 256 + tid;
    float4 v = ((const float4*)src)[i];
    union { unsigned long long ll; u16 s[4]; } o;
    o.s[0] = f2bf(v.x); o.s[1] = f2bf(v.y); o.s[2] = f2bf(v.z); o.s[3] = f2bf(v.w);
    ((unsigned long long*)dst)[i] = o.ll;
    return;
  }
  int id = (bid - 5120) * 256 + tid;  // 786432 total
  int kk4 = id & 15;
  int d = (id >> 4) & 1023;
  int h = (id >> 14) & 15;
  int wsel = id >> 18;
  const float* W = wsel == 0 ? Wq : (wsel == 1 ? Wk : Wv);
  float4 v = *(const float4*)(W + ((size_t)(h * 1024 + d)) * 64 + kk4 * 4);
  int nb = wsel * 1024 + h * 64 + kk4 * 4;
  Wt[(size_t)(nb + 0) * 1024 + d] = f2bf(v.x);
  Wt[(size_t)(nb + 1) * 1024 + d] = f2bf(v.y);
  Wt[(size_t)(nb + 2) * 1024 + d] = f2bf(v.z);
  Wt[(size_t)(nb + 3) * 1024 + d] = f2bf(v.w);
  if (id < 3072) {
    int ws2 = id >> 10, hk = id & 1023;
    const float* bsrc = ws2 == 0 ? bq : (ws2 == 1 ? bk : bv);
    ball[id] = bsrc[hk];
  }
}

// ---------------- GEMM: C[M,N] = A[M,K] * B^T (B stored [N,K]) + bias, opt scale --------------
// 1-D grid, XCD-swizzled: xcd owns bm cluster of 4 (keeps A-tiles in per-XCD L2).
// BK=64: two compute phases per barrier pair (halves the vmcnt(0)+s_barrier drains).
// Staged tiles are XOR-swizzled on 8-elem chunks (chunk ^= row&7), applied on the DMA
// source side so async16's linear-dest constraint holds; fragment ds_read_b128 lanes
// then spread over all banks (~2-way, free) instead of 16-way at stride-64.
// SPLITV (QKV mode): cols >= 2048 (the V projection) are written DIRECTLY in the Vtc
// attention layout [bh][chunk s/16][oct (s%16)/8][d][s%8], 4 bf16 packed per 8B store.

__device__ __forceinline__ void store_out(u16* p, float v) { *p = f2bf(v); }
__device__ __forceinline__ void store_out(float* p, float v) { *p = v; }

template <int BN, bool SPLITV, typename OutT>
__global__ __launch_bounds__(256) void gemm_bt(
    const u16* __restrict__ A, const u16* __restrict__ B,
    const float* __restrict__ bias, OutT* __restrict__ C,
    u16* __restrict__ Vtc,
    int M, int N, int K, int scaleNend, float scaleVal) {
  constexpr int TN = BN / 32;  // n-tiles per wave
  __shared__ __attribute__((aligned(16))) u16 As[128 * 64];
  __shared__ __attribute__((aligned(16))) u16 Bs[BN * 64];
  const int tid = threadIdx.x;
  const int w = tid >> 6, lane = tid & 63;
  const int l15 = lane & 15, l4 = lane >> 4;
  const int lin = blockIdx.x;
  const int xcd = lin & 7, sblk = lin >> 3;
  const int bm = xcd * 4 + (sblk & 3);   // M=4096 -> 32 bm tiles, 4 per XCD
  const int bn = sblk >> 2;
  const int wm = (w & 1) * 64, wn = (w >> 1) * (BN / 2);

  floatx4 acc[4][TN];
#pragma unroll
  for (int i = 0; i < 4; ++i)
#pragma unroll
    for (int j = 0; j < TN; ++j) acc[i][j] = (floatx4){0.f, 0.f, 0.f, 0.f};

  for (int k0 = 0; k0 < K; k0 += 64) {
    __syncthreads();
#pragma unroll
    for (int j = 0; j < 4; ++j) {  // A: 128 rows x 8 chunks = 1024 slots
      int i = j * 256 + tid;
      int row = i >> 3, c = (i & 7) ^ (row & 7);
      async16(A + (size_t)(bm * 128 + row) * K + k0 + c * 8, As + (j * 256 + w * 64) * 8);
    }
#pragma unroll
    for (int j = 0; j < BN / 32; ++j) {  // B: BN rows x 8 chunks
      int i = j * 256 + tid;
      int row = i >> 3, c = (i & 7) ^ (row & 7);
      async16(B + (size_t)(bn * BN + row) * K + k0 + c * 8, Bs + (j * 256 + w * 64) * 8);
    }
    __syncthreads();
    const int sw = l15 & 7;
#pragma unroll
    for (int ks = 0; ks < 2; ++ks) {
      short8 af[4], bf[TN];
#pragma unroll
      for (int t = 0; t < 4; ++t)
        af[t] = *(const short8*)(As + (wm + t * 16 + l15) * 64 + (((ks * 4 + l4) ^ sw)) * 8);
#pragma unroll
      for (int t = 0; t < TN; ++t)
        bf[t] = *(const short8*)(Bs + (wn + t * 16 + l15) * 64 + (((ks * 4 + l4) ^ sw)) * 8);
#pragma unroll
      for (int tm = 0; tm < 4; ++tm)
#pragma unroll
        for (int tn = 0; tn < TN; ++tn) acc[tm][tn] = MFMA16(af[tm], bf[tn], acc[tm][tn]);
    }
  }

#pragma unroll
  for (int tn = 0; tn < TN; ++tn) {
    int col = bn * BN + wn + tn * 16 + l15;
    float bv = bias[col];
    float sc = (col < scaleNend) ? scaleVal : 1.0f;
    if (!SPLITV || col < 2048) {
#pragma unroll
      for (int tm = 0; tm < 4; ++tm) {
        int row0 = bm * 128 + wm + tm * 16 + l4 * 4;
#pragma unroll
        for (int r = 0; r < 4; ++r) {
          float v = (acc[tm][tn][r] + bv) * sc;
          store_out(C + (size_t)(row0 + r) * N + col, v);
        }
      }
    } else {
      int hv = (col - 2048) >> 6, d = (col - 2048) & 63;
#pragma unroll
      for (int tm = 0; tm < 4; ++tm) {
        int row0 = bm * 128 + wm + tm * 16 + l4 * 4;
        int bb = row0 >> 11, s0 = row0 & 2047;
        union { unsigned long long ll; u16 s[4]; } o;
#pragma unroll
        for (int r = 0; r < 4; ++r) o.s[r] = f2bf(acc[tm][tn][r] + bv);
        // rows row0..row0+3 are consecutive (s&7) slots of one octet -> one 8B store
        size_t idx = ((((size_t)(bb * 16 + hv) * 128 + (s0 >> 4)) * 2 + ((s0 >> 3) & 1)) * 64 + d) * 8 +
                     (s0 & 7);
        *(unsigned long long*)(Vtc + idx) = o.ll;
      }
    }
  }
}

// ---------------- attention (round-6 proven: barrier-free, register-direct K/V) ----------------
// Block: 64 q-rows of one (b,h); wave w owns keys [w*512,(w+1)*512), ALL 64 q-rows (tq=4).
// K and V fragments are loaded straight from L2 to VGPRs (plain dwordx4 per lane; MFMA
// fragment = 16B contiguous per lane) -- NO global_load_lds, NO staging LDS, NO barriers
// in the key loop, so there is no vmcnt(0)+s_barrier drain.
// LDS is only the per-wave P round-trip + one-time cross-wave O/l combine (1 barrier).
// XCD swizzle: 4 bh per XCD -> K/V (2MB) L2-resident (r3: FETCH 12.5MB).
// Q pre-scaled by log2(e)/8 -> raw exp2; unnormalized accumulate (flat softmax, max-free
// safe); divide once at the end. [r9 lesson: NO manual register double-buffering --
// lambda-rotated K buffers made the compiler spill 540 MB of scratch traffic.]

__global__ __launch_bounds__(256, 3) void attn_kernel(const u16* __restrict__ QKV,
                                                      const u16* __restrict__ Vtc,
                                                      u16* __restrict__ Ob) {
  // per-wave region: 4736 u16 = P[64 q][stride 40] (2560) overlapped by
  // Osum bf16 [64][stride 72] (4608) + l f32[64] at offset 4608.
  __shared__ __attribute__((aligned(16))) u16 lds[4 * 4736];  // 37888 B
  const int tid = threadIdx.x;
  const int w = tid >> 6, lane = tid & 63;
  const int l15 = lane & 15, l4 = lane >> 4;
  const int lin = blockIdx.x;                 // 1024 blocks
  const int xcd = lin & 7, sblk = lin >> 3;   // sblk in [0,128)
  const int bh = xcd * 4 + (sblk & 3);        // 4 bh per XCD
  const int q0 = (sblk >> 2) * 64;            // 32 q-tiles of 64
  const int b = bh >> 4, h = bh & 15;

  u16* const Pw = lds + w * 4736;

  // Q fragments (B-operand of S^T): rows q0 + tq*16 + l15, k(d) = s*32 + l4*8
  short8 qf[4][2];
  {
    const u16* Qb = QKV + (size_t)(b * 2048 + q0) * 3072 + h * 64;
#pragma unroll
    for (int tq = 0; tq < 4; ++tq)
#pragma unroll
      for (int s = 0; s < 2; ++s)
        qf[tq][s] = *(const short8*)(Qb + (size_t)(tq * 16 + l15) * 3072 + s * 32 + l4 * 8);
  }

  floatx4 Oacc[4][4];
#pragma unroll
  for (int i = 0; i < 4; ++i)
#pragma unroll
    for (int j = 0; j < 4; ++j) Oacc[i][j] = (floatx4){0.f, 0.f, 0.f, 0.f};
  float lpart[4] = {0.f, 0.f, 0.f, 0.f};

  const u16* const Kb = QKV + (size_t)(b * 2048) * 3072 + 1024 + h * 64;  // + key*3072
  const u16* const Vw = Vtc + (size_t)bh * 131072 + (size_t)w * 32768;    // wave's 512 keys
  const int kw0 = w * 512;

  for (int c = 0; c < 16; ++c) {  // 32-key supersteps
    const int key0 = kw0 + c * 32;
    // K fragments (A-operand): A[m=key][k=d]; lane: key = key0 + t*16 + l15, d = s*32+l4*8
    short8 kf[2][2];
#pragma unroll
    for (int t = 0; t < 2; ++t)
#pragma unroll
      for (int s = 0; s < 2; ++s)
        kf[t][s] = *(const short8*)(Kb + (size_t)(key0 + t * 16 + l15) * 3072 + s * 32 + l4 * 8);
    // V fragments (B-operand): B[n=d][k=key]; lane: d = td*16+l15, keys l4*8..+8
    short8 vf[4];
#pragma unroll
    for (int td = 0; td < 4; ++td)
      vf[td] = *(const short8*)(Vw + (size_t)c * 2048 + l4 * 512 + (td * 16 + l15) * 8);

    // S^T: C[key16][q16]; row=key=l4*4+r, col=q=l15
#pragma unroll
    for (int t = 0; t < 2; ++t)
#pragma unroll
      for (int tq = 0; tq < 4; ++tq) {
        floatx4 s = (floatx4){0.f, 0.f, 0.f, 0.f};
        s = MFMA16(kf[t][0], qf[tq][0], s);
        s = MFMA16(kf[t][1], qf[tq][1], s);
        float p0 = fexp2(s[0]), p1 = fexp2(s[1]), p2 = fexp2(s[2]), p3 = fexp2(s[3]);
        lpart[tq] += (p0 + p1) + (p2 + p3);
        unsigned lo = pk2(p1, p0), hi = pk2(p3, p2);
        *(unsigned long long*)(Pw + (size_t)(tq * 16 + l15) * 40 + t * 16 + l4 * 4) =
            ((unsigned long long)hi << 32) | lo;
      }

    // PV: O[q][d] += P[q][k32] * V[k32][d]
    short8 pf[4];
#pragma unroll
    for (int tq = 0; tq < 4; ++tq)
      pf[tq] = *(const short8*)(Pw + (size_t)(tq * 16 + l15) * 40 + l4 * 8);
#pragma unroll
    for (int td = 0; td < 4; ++td)
#pragma unroll
      for (int tq = 0; tq < 4; ++tq) Oacc[tq][td] = MFMA16(pf[tq], vf[td], Oacc[tq][td]);
  }

  // per-wave l reduction across l4 key-groups (full 512-key sums per q)
  float lr[4];
#pragma unroll
  for (int tq = 0; tq < 4; ++tq) {
    float l = lpart[tq];
    l += __shfl_xor(l, 16);
    l += __shfl_xor(l, 32);
    lr[tq] = l;
  }

  // write per-wave partials (own region; own P reads already retired in-order)
#pragma unroll
  for (int tq = 0; tq < 4; ++tq)
#pragma unroll
    for (int td = 0; td < 4; ++td)
#pragma unroll
      for (int r = 0; r < 4; ++r)
        Pw[(size_t)(tq * 16 + l4 * 4 + r) * 72 + td * 16 + l15] = f2bf(Oacc[tq][td][r]);
  if (l4 == 0) {
    float* Lw = (float*)(Pw + 4608);
#pragma unroll
    for (int tq = 0; tq < 4; ++tq) Lw[tq * 16 + l15] = lr[tq];
  }
  __syncthreads();

  // combine: thread -> (row = tid>>2 of 64, 16 cols); sum 4 wave partials
  {
    int row = tid >> 2, c0 = (tid & 3) * 16;
    float acc[16];
#pragma unroll
    for (int j = 0; j < 16; ++j) acc[j] = 0.f;
    float lsum = 0.f;
#pragma unroll
    for (int wv = 0; wv < 4; ++wv) {
      const u16* R = lds + wv * 4736;
      lsum += ((const float*)(R + 4608))[row];
      U128u x1, x2;
      x1.q = *(const uint4*)(R + (size_t)row * 72 + c0);
      x2.q = *(const uint4*)(R + (size_t)row * 72 + c0 + 8);
#pragma unroll
      for (int j = 0; j < 8; ++j) { acc[j] += bf2f(x1.s[j]); acc[8 + j] += bf2f(x2.s[j]); }
    }
    float inv = 1.0f / lsum;
    U128u o1, o2;
#pragma unroll
    for (int j = 0; j < 8; ++j) { o1.s[j] = f2bf(acc[j] * inv); o2.s[j] = f2bf(acc[8 + j] * inv); }
    u16* Op = Ob + (size_t)(b * 2048 + q0 + row) * 1024 + h * 64 + c0;
    *(uint4*)Op = o1.q;
    *(uint4*)(Op + 8) = o2.q;
  }
}

// ---------------- launch ----------------

extern "C" void kernel_launch(void* const* d_in, const int* in_sizes, int n_in,
                              void* d_out, int out_size, void* d_ws, size_t ws_size,
                              hipStream_t stream) {
  const float* x  = (const float*)d_in[0];
  const float* Wq = (const float*)d_in[1];
  const float* bq = (const float*)d_in[2];
  const float* Wk = (const float*)d_in[3];
  const float* bk = (const float*)d_in[4];
  const float* Wv = (const float*)d_in[5];
  const float* bv = (const float*)d_in[6];
  const float* Wo = (const float*)d_in[7];
  const float* bo = (const float*)d_in[8];

  char* p = (char*)d_ws;
  u16* Xb   = (u16*)p; p += (size_t)4096 * 1024 * 2;   // x bf16
  u16* Wt   = (u16*)p; p += (size_t)3072 * 1024 * 2;   // W_all^T bf16 [n][d]
  u16* QKV  = (u16*)p; p += (size_t)4096 * 3072 * 2;   // [token][3072] bf16; Q pre-scaled, V third unused
  u16* Vtc  = (u16*)p; p += (size_t)32 * 128 * 2 * 64 * 8 * 2;  // V chunked: [bh][v][o][d][k8]
  u16* Ob   = (u16*)p; p += (size_t)4096 * 1024 * 2;   // attention out bf16 (normalized)
  u16* Wob  = (u16*)p; p += (size_t)1024 * 1024 * 2;   // Wo bf16 [e][d]
  float* ball = (float*)p; p += 3072 * sizeof(float);

  const float qscale = 0.125f * 1.4426950408889634f;  // (1/sqrt(64)) * log2(e)

  prep_all<<<8192, 256, 0, stream>>>(x, Wo, Wq, bq, Wk, bk, Wv, bv, Xb, Wob, Wt, ball);
  gemm_bt<128, true, u16><<<768, 256, 0, stream>>>(Xb, Wt, ball, QKV, Vtc,
                                                   4096, 3072, 1024, 1024, qscale);
  attn_kernel<<<1024, 256, 0, stream>>>(QKV, Vtc, Ob);
  gemm_bt<64, false, float><<<512, 256, 0, stream>>>(Ob, Wob, bo, (float*)d_out, nullptr,
                                                     4096, 1024, 1024, 0, 1.0f);
}

// Round 12
// 204.730 us; speedup vs baseline: 1.5936x; 1.0436x over previous
//
#include <hip/hip_runtime.h>
#include <hip/hip_bf16.h>

typedef unsigned short u16;
typedef short short8 __attribute__((ext_vector_type(8)));
typedef float floatx4 __attribute__((ext_vector_type(4)));

#define MFMA16(a, b, c) __builtin_amdgcn_mfma_f32_16x16x32_bf16((a), (b), (c), 0, 0, 0)

union U128u { uint4 q; u16 s[8]; };

__device__ __forceinline__ u16 f2bf(float f) {
  union { float f; unsigned u; } v; v.f = f;
  unsigned r = v.u + 0x7fffu + ((v.u >> 16) & 1u);
  return (u16)(r >> 16);
}

__device__ __forceinline__ float bf2f(u16 s) {
  union { unsigned u; float f; } v; v.u = ((unsigned)s) << 16;
  return v.f;
}

// pack two f32 -> bf16x2 (round-half-up) with one v_perm (attn P only)
__device__ __forceinline__ unsigned pk2(float hi, float lo) {
  union { float f; unsigned u; } a, b;
  a.f = hi; b.f = lo;
  return __builtin_amdgcn_perm(a.u + 0x8000u, b.u + 0x8000u, 0x07060302u);
}

__device__ __forceinline__ float fexp2(float x) {
#if __has_builtin(__builtin_amdgcn_exp2f)
  return __builtin_amdgcn_exp2f(x);
#else
  return exp2f(x);
#endif
}

// async global->LDS, 16B per lane. lds pointer must be wave-uniform. (GEMMs only.)
__device__ __forceinline__ void async16(const u16* g, u16* l) {
  __builtin_amdgcn_global_load_lds(
      (const __attribute__((address_space(1))) unsigned int*)g,
      (__attribute__((address_space(3))) unsigned int*)l, 16, 0, 0);
}

// ---------------- merged prep: cast x, cast Wo, repack Wqkv + biases ----------------

__global__ __launch_bounds__(256) void prep_all(
    const float* __restrict__ x, const float* __restrict__ Wo,
    const float* __restrict__ Wq, const float* __restrict__ bq,
    const float* __restrict__ Wk, const float* __restrict__ bk,
    const float* __restrict__ Wv, const float* __restrict__ bv,
    u16* __restrict__ Xb, u16* __restrict__ Wob,
    u16* __restrict__ Wt, float* __restrict__ ball) {
  int bid = blockIdx.x;
  int tid = threadIdx.x;
  if (bid < 5120) {
    // cast: blocks [0,4096) -> x (1048576 float4), [4096,5120) -> Wo (262144 float4)
    const float* src = bid < 4096 ? x : Wo;
    u16* dst = bid < 4096 ? Xb : Wob;
    int i = (bid < 4096 ? bid : bid - 4096) * 256 + tid;
    float4 v = ((const float4*)src)[i];
    union { unsigned long long ll; u16 s[4]; } o;
    o.s[0] = f2bf(v.x); o.s[1] = f2bf(v.y); o.s[2] = f2bf(v.z); o.s[3] = f2bf(v.w);
    ((unsigned long long*)dst)[i] = o.ll;
    return;
  }
  int id = (bid - 5120) * 256 + tid;  // 786432 total
  int kk4 = id & 15;
  int d = (id >> 4) & 1023;
  int h = (id >> 14) & 15;
  int wsel = id >> 18;
  const float* W = wsel == 0 ? Wq : (wsel == 1 ? Wk : Wv);
  float4 v = *(const float4*)(W + ((size_t)(h * 1024 + d)) * 64 + kk4 * 4);
  int nb = wsel * 1024 + h * 64 + kk4 * 4;
  Wt[(size_t)(nb + 0) * 1024 + d] = f2bf(v.x);
  Wt[(size_t)(nb + 1) * 1024 + d] = f2bf(v.y);
  Wt[(size_t)(nb + 2) * 1024 + d] = f2bf(v.z);
  Wt[(size_t)(nb + 3) * 1024 + d] = f2bf(v.w);
  if (id < 3072) {
    int ws2 = id >> 10, hk = id & 1023;
    const float* bsrc = ws2 == 0 ? bq : (ws2 == 1 ? bk : bv);
    ball[id] = bsrc[hk];
  }
}

// ---------------- GEMM: C[M,N] = A[M,K] * B^T (B stored [N,K]) + bias, opt scale --------------
// 1-D grid, XCD-swizzled: xcd owns bm cluster of 4 (keeps A-tiles in per-XCD L2).
// BK=64, staged tiles XOR-swizzled on 8-elem chunks (DMA-source side; async16 dest linear).
// SPLITV (QKV mode): cols >= 2048 (the V projection) are written DIRECTLY in the Vtc
// attention layout [bh][chunk s/16][oct (s%16)/8][d][s%8], 4 bf16 packed per 8B store.
// TRANS (out-proj mode): MFMA operands swapped so each lane holds 4 CONSECUTIVE COLUMNS
// of one row -> epilogue is float4 stores (16B/lane) instead of 64 scalar stores.

__device__ __forceinline__ void store_out(u16* p, float v) { *p = f2bf(v); }
__device__ __forceinline__ void store_out(float* p, float v) { *p = v; }

template <int BN, bool SPLITV, bool TRANS, typename OutT>
__global__ __launch_bounds__(256, 4) void gemm_bt(
    const u16* __restrict__ A, const u16* __restrict__ B,
    const float* __restrict__ bias, OutT* __restrict__ C,
    u16* __restrict__ Vtc,
    int M, int N, int K, int scaleNend, float scaleVal) {
  constexpr int TN = BN / 32;  // n-tiles per wave
  __shared__ __attribute__((aligned(16))) u16 As[128 * 64];
  __shared__ __attribute__((aligned(16))) u16 Bs[BN * 64];
  const int tid = threadIdx.x;
  const int w = tid >> 6, lane = tid & 63;
  const int l15 = lane & 15, l4 = lane >> 4;
  const int lin = blockIdx.x;
  const int xcd = lin & 7, sblk = lin >> 3;
  const int bm = xcd * 4 + (sblk & 3);   // M=4096 -> 32 bm tiles, 4 per XCD
  const int bn = sblk >> 2;
  const int wm = (w & 1) * 64, wn = (w >> 1) * (BN / 2);

  floatx4 acc[4][TN];
#pragma unroll
  for (int i = 0; i < 4; ++i)
#pragma unroll
    for (int j = 0; j < TN; ++j) acc[i][j] = (floatx4){0.f, 0.f, 0.f, 0.f};

  for (int k0 = 0; k0 < K; k0 += 64) {
    __syncthreads();
#pragma unroll
    for (int j = 0; j < 4; ++j) {  // A: 128 rows x 8 chunks = 1024 slots
      int i = j * 256 + tid;
      int row = i >> 3, c = (i & 7) ^ (row & 7);
      async16(A + (size_t)(bm * 128 + row) * K + k0 + c * 8, As + (j * 256 + w * 64) * 8);
    }
#pragma unroll
    for (int j = 0; j < BN / 32; ++j) {  // B: BN rows x 8 chunks
      int i = j * 256 + tid;
      int row = i >> 3, c = (i & 7) ^ (row & 7);
      async16(B + (size_t)(bn * BN + row) * K + k0 + c * 8, Bs + (j * 256 + w * 64) * 8);
    }
    __syncthreads();
    const int sw = l15 & 7;
#pragma unroll
    for (int ks = 0; ks < 2; ++ks) {
      short8 af[4], bf[TN];
#pragma unroll
      for (int t = 0; t < 4; ++t)
        af[t] = *(const short8*)(As + (wm + t * 16 + l15) * 64 + (((ks * 4 + l4) ^ sw)) * 8);
#pragma unroll
      for (int t = 0; t < TN; ++t)
        bf[t] = *(const short8*)(Bs + (wn + t * 16 + l15) * 64 + (((ks * 4 + l4) ^ sw)) * 8);
#pragma unroll
      for (int tm = 0; tm < 4; ++tm)
#pragma unroll
        for (int tn = 0; tn < TN; ++tn)
          acc[tm][tn] = TRANS ? MFMA16(bf[tn], af[tm], acc[tm][tn])
                              : MFMA16(af[tm], bf[tn], acc[tm][tn]);
    }
  }

  if (TRANS) {
    // acc holds transposed fragments: lane l15 -> row (A index), l4*4+r -> col (B index)
#pragma unroll
    for (int tn = 0; tn < TN; ++tn) {
      int colb = bn * BN + wn + tn * 16 + l4 * 4;
      float4 bv4 = *(const float4*)(bias + colb);
#pragma unroll
      for (int tm = 0; tm < 4; ++tm) {
        int row = bm * 128 + wm + tm * 16 + l15;
        float4 v;
        v.x = acc[tm][tn][0] + bv4.x;
        v.y = acc[tm][tn][1] + bv4.y;
        v.z = acc[tm][tn][2] + bv4.z;
        v.w = acc[tm][tn][3] + bv4.w;
        *(float4*)((float*)C + (size_t)row * N + colb) = v;
      }
    }
    return;
  }

#pragma unroll
  for (int tn = 0; tn < TN; ++tn) {
    int col = bn * BN + wn + tn * 16 + l15;
    float bv = bias[col];
    float sc = (col < scaleNend) ? scaleVal : 1.0f;
    if (!SPLITV || col < 2048) {
#pragma unroll
      for (int tm = 0; tm < 4; ++tm) {
        int row0 = bm * 128 + wm + tm * 16 + l4 * 4;
#pragma unroll
        for (int r = 0; r < 4; ++r) {
          float v = (acc[tm][tn][r] + bv) * sc;
          store_out(C + (size_t)(row0 + r) * N + col, v);
        }
      }
    } else {
      int hv = (col - 2048) >> 6, d = (col - 2048) & 63;
#pragma unroll
      for (int tm = 0; tm < 4; ++tm) {
        int row0 = bm * 128 + wm + tm * 16 + l4 * 4;
        int bb = row0 >> 11, s0 = row0 & 2047;
        union { unsigned long long ll; u16 s[4]; } o;
#pragma unroll
        for (int r = 0; r < 4; ++r) o.s[r] = f2bf(acc[tm][tn][r] + bv);
        // rows row0..row0+3 are consecutive (s&7) slots of one octet -> one 8B store
        size_t idx = ((((size_t)(bb * 16 + hv) * 128 + (s0 >> 4)) * 2 + ((s0 >> 3) & 1)) * 64 + d) * 8 +
                     (s0 & 7);
        *(unsigned long long*)(Vtc + idx) = o.ll;
      }
    }
  }
}

// ---------------- attention (round-6 proven: barrier-free, register-direct K/V) ----------------
// Block: 64 q-rows of one (b,h); wave w owns keys [w*512,(w+1)*512), ALL 64 q-rows (tq=4).
// K and V fragments are loaded straight from L2 to VGPRs (plain dwordx4 per lane; MFMA
// fragment = 16B contiguous per lane) -- NO global_load_lds, NO staging LDS, NO barriers
// in the key loop, so there is no vmcnt(0)+s_barrier drain.
// LDS is only the per-wave P round-trip + one-time cross-wave O/l combine (1 barrier).
// XCD swizzle: 4 bh per XCD -> K/V (2MB) L2-resident (r3: FETCH 12.5MB).
// Q pre-scaled by log2(e)/8 -> raw exp2; unnormalized accumulate (flat softmax, max-free
// safe); divide once at the end. [r9 lesson: NO manual register double-buffering --
// lambda-rotated K buffers made the compiler spill 540 MB of scratch traffic.]

__global__ __launch_bounds__(256, 3) void attn_kernel(const u16* __restrict__ QKV,
                                                      const u16* __restrict__ Vtc,
                                                      u16* __restrict__ Ob) {
  // per-wave region: 4736 u16 = P[64 q][stride 40] (2560) overlapped by
  // Osum bf16 [64][stride 72] (4608) + l f32[64] at offset 4608.
  __shared__ __attribute__((aligned(16))) u16 lds[4 * 4736];  // 37888 B
  const int tid = threadIdx.x;
  const int w = tid >> 6, lane = tid & 63;
  const int l15 = lane & 15, l4 = lane >> 4;
  const int lin = blockIdx.x;                 // 1024 blocks
  const int xcd = lin & 7, sblk = lin >> 3;   // sblk in [0,128)
  const int bh = xcd * 4 + (sblk & 3);        // 4 bh per XCD
  const int q0 = (sblk >> 2) * 64;            // 32 q-tiles of 64
  const int b = bh >> 4, h = bh & 15;

  u16* const Pw = lds + w * 4736;

  // Q fragments (B-operand of S^T): rows q0 + tq*16 + l15, k(d) = s*32 + l4*8
  short8 qf[4][2];
  {
    const u16* Qb = QKV + (size_t)(b * 2048 + q0) * 3072 + h * 64;
#pragma unroll
    for (int tq = 0; tq < 4; ++tq)
#pragma unroll
      for (int s = 0; s < 2; ++s)
        qf[tq][s] = *(const short8*)(Qb + (size_t)(tq * 16 + l15) * 3072 + s * 32 + l4 * 8);
  }

  floatx4 Oacc[4][4];
#pragma unroll
  for (int i = 0; i < 4; ++i)
#pragma unroll
    for (int j = 0; j < 4; ++j) Oacc[i][j] = (floatx4){0.f, 0.f, 0.f, 0.f};
  float lpart[4] = {0.f, 0.f, 0.f, 0.f};

  const u16* const Kb = QKV + (size_t)(b * 2048) * 3072 + 1024 + h * 64;  // + key*3072
  const u16* const Vw = Vtc + (size_t)bh * 131072 + (size_t)w * 32768;    // wave's 512 keys
  const int kw0 = w * 512;

  for (int c = 0; c < 16; ++c) {  // 32-key supersteps
    const int key0 = kw0 + c * 32;
    // K fragments (A-operand): A[m=key][k=d]; lane: key = key0 + t*16 + l15, d = s*32+l4*8
    short8 kf[2][2];
#pragma unroll
    for (int t = 0; t < 2; ++t)
#pragma unroll
      for (int s = 0; s < 2; ++s)
        kf[t][s] = *(const short8*)(Kb + (size_t)(key0 + t * 16 + l15) * 3072 + s * 32 + l4 * 8);
    // V fragments (B-operand): B[n=d][k=key]; lane: d = td*16+l15, keys l4*8..+8
    short8 vf[4];
#pragma unroll
    for (int td = 0; td < 4; ++td)
      vf[td] = *(const short8*)(Vw + (size_t)c * 2048 + l4 * 512 + (td * 16 + l15) * 8);

    // S^T: C[key16][q16]; row=key=l4*4+r, col=q=l15
#pragma unroll
    for (int t = 0; t < 2; ++t)
#pragma unroll
      for (int tq = 0; tq < 4; ++tq) {
        floatx4 s = (floatx4){0.f, 0.f, 0.f, 0.f};
        s = MFMA16(kf[t][0], qf[tq][0], s);
        s = MFMA16(kf[t][1], qf[tq][1], s);
        float p0 = fexp2(s[0]), p1 = fexp2(s[1]), p2 = fexp2(s[2]), p3 = fexp2(s[3]);
        lpart[tq] += (p0 + p1) + (p2 + p3);
        unsigned lo = pk2(p1, p0), hi = pk2(p3, p2);
        *(unsigned long long*)(Pw + (size_t)(tq * 16 + l15) * 40 + t * 16 + l4 * 4) =
            ((unsigned long long)hi << 32) | lo;
      }

    // PV: O[q][d] += P[q][k32] * V[k32][d]
    short8 pf[4];
#pragma unroll
    for (int tq = 0; tq < 4; ++tq)
      pf[tq] = *(const short8*)(Pw + (size_t)(tq * 16 + l15) * 40 + l4 * 8);
#pragma unroll
    for (int td = 0; td < 4; ++td)
#pragma unroll
      for (int tq = 0; tq < 4; ++tq) Oacc[tq][td] = MFMA16(pf[tq], vf[td], Oacc[tq][td]);
  }

  // per-wave l reduction across l4 key-groups (full 512-key sums per q)
  float lr[4];
#pragma unroll
  for (int tq = 0; tq < 4; ++tq) {
    float l = lpart[tq];
    l += __shfl_xor(l, 16);
    l += __shfl_xor(l, 32);
    lr[tq] = l;
  }

  // write per-wave partials (own region; own P reads already retired in-order)
#pragma unroll
  for (int tq = 0; tq < 4; ++tq)
#pragma unroll
    for (int td = 0; td < 4; ++td)
#pragma unroll
      for (int r = 0; r < 4; ++r)
        Pw[(size_t)(tq * 16 + l4 * 4 + r) * 72 + td * 16 + l15] = f2bf(Oacc[tq][td][r]);
  if (l4 == 0) {
    float* Lw = (float*)(Pw + 4608);
#pragma unroll
    for (int tq = 0; tq < 4; ++tq) Lw[tq * 16 + l15] = lr[tq];
  }
  __syncthreads();

  // combine: thread -> (row = tid>>2 of 64, 16 cols); sum 4 wave partials
  {
    int row = tid >> 2, c0 = (tid & 3) * 16;
    float acc[16];
#pragma unroll
    for (int j = 0; j < 16; ++j) acc[j] = 0.f;
    float lsum = 0.f;
#pragma unroll
    for (int wv = 0; wv < 4; ++wv) {
      const u16* R = lds + wv * 4736;
      lsum += ((const float*)(R + 4608))[row];
      U128u x1, x2;
      x1.q = *(const uint4*)(R + (size_t)row * 72 + c0);
      x2.q = *(const uint4*)(R + (size_t)row * 72 + c0 + 8);
#pragma unroll
      for (int j = 0; j < 8; ++j) { acc[j] += bf2f(x1.s[j]); acc[8 + j] += bf2f(x2.s[j]); }
    }
    float inv = 1.0f / lsum;
    U128u o1, o2;
#pragma unroll
    for (int j = 0; j < 8; ++j) { o1.s[j] = f2bf(acc[j] * inv); o2.s[j] = f2bf(acc[8 + j] * inv); }
    u16* Op = Ob + (size_t)(b * 2048 + q0 + row) * 1024 + h * 64 + c0;
    *(uint4*)Op = o1.q;
    *(uint4*)(Op + 8) = o2.q;
  }
}

// ---------------- launch ----------------

extern "C" void kernel_launch(void* const* d_in, const int* in_sizes, int n_in,
                              void* d_out, int out_size, void* d_ws, size_t ws_size,
                              hipStream_t stream) {
  const float* x  = (const float*)d_in[0];
  const float* Wq = (const float*)d_in[1];
  const float* bq = (const float*)d_in[2];
  const float* Wk = (const float*)d_in[3];
  const float* bk = (const float*)d_in[4];
  const float* Wv = (const float*)d_in[5];
  const float* bv = (const float*)d_in[6];
  const float* Wo = (const float*)d_in[7];
  const float* bo = (const float*)d_in[8];

  char* p = (char*)d_ws;
  u16* Xb   = (u16*)p; p += (size_t)4096 * 1024 * 2;   // x bf16
  u16* Wt   = (u16*)p; p += (size_t)3072 * 1024 * 2;   // W_all^T bf16 [n][d]
  u16* QKV  = (u16*)p; p += (size_t)4096 * 3072 * 2;   // [token][3072] bf16; Q pre-scaled, V third unused
  u16* Vtc  = (u16*)p; p += (size_t)32 * 128 * 2 * 64 * 8 * 2;  // V chunked: [bh][v][o][d][k8]
  u16* Ob   = (u16*)p; p += (size_t)4096 * 1024 * 2;   // attention out bf16 (normalized)
  u16* Wob  = (u16*)p; p += (size_t)1024 * 1024 * 2;   // Wo bf16 [e][d]
  float* ball = (float*)p; p += 3072 * sizeof(float);

  const float qscale = 0.125f * 1.4426950408889634f;  // (1/sqrt(64)) * log2(e)

  prep_all<<<8192, 256, 0, stream>>>(x, Wo, Wq, bq, Wk, bk, Wv, bv, Xb, Wob, Wt, ball);
  // QKV: BN=96 -> 32x32 = 1024 blocks = 4 blocks/CU (occupancy; was 768 = 3/CU)
  gemm_bt<96, true, false, u16><<<1024, 256, 0, stream>>>(Xb, Wt, ball, QKV, Vtc,
                                                          4096, 3072, 1024, 1024, qscale);
  attn_kernel<<<1024, 256, 0, stream>>>(QKV, Vtc, Ob);
  // out-proj: TRANS epilogue -> float4 stores
  gemm_bt<64, false, true, float><<<512, 256, 0, stream>>>(Ob, Wob, bo, (float*)d_out, nullptr,
                                                           4096, 1024, 1024, 0, 1.0f);
}